// Round 1
// baseline (261.394 us; speedup 1.0000x reference)
//
#include <hip/hip_runtime.h>
#include <stdint.h>

// ---------------------------------------------------------------------------
// BailingMoE block: T=1024, H=1024, E=16, top-4, I=512 routed, Is=1024 shared
// R8: latency-bound fix. phase1/phase2 re-tiled 128x64/4-wave/3-stage ->
// 64x64/2-wave/4-stage. Same per-wave shape (64m x 32j, 8 MFMA/step) but
// ~2x independent block pipelines per CU (5 resident @ 32KB LDS) and one
// more stage of prefetch lookahead (vmcnt(8): 3 stages = 12 loads in flight
// per wave). Grid y-tiles 64 rows.
// ---------------------------------------------------------------------------

typedef __attribute__((ext_vector_type(8))) unsigned short ushort8;
typedef __attribute__((ext_vector_type(4))) float f32x4;
typedef __attribute__((ext_vector_type(8))) __bf16 bf16x8;

#define T_TOK 1024
#define HID   1024
#define NEXP  16
#define TOPK  4
#define MINTER 512
#define SINTER 1024

constexpr size_t WGU_E = 32 * 1024 * 32;   // per-expert gate/up panels
constexpr size_t WD_E  = 16 * 1024 * 32;   // per-expert down panels

constexpr size_t OFF_COUNTS = 0;
constexpr size_t OFF_LIST   = 1024;
constexpr size_t OFF_WT     = OFF_LIST  + 65536;
constexpr size_t OFF_TIDX   = OFF_WT    + 65536;
constexpr size_t OFF_XB     = OFF_TIDX  + 65536;               // bf16 [1024][1024]
constexpr size_t OFF_HR     = OFF_XB    + 2097152;             // bf16 [16][4096][32]
constexpr size_t OFF_HS     = OFF_HR    + 4194304;             // bf16 [32][1024][32]
constexpr size_t OFF_WGU    = OFF_HS    + 2097152;             // bf16 [16]xWGU_E
constexpr size_t OFF_WD     = OFF_WGU   + 33554432;            // bf16 [16]xWD_E
constexpr size_t OFF_WSGU   = OFF_WD    + 16777216;            // bf16 [32][2048][32]
constexpr size_t OFF_WSD    = OFF_WSGU  + 4194304;             // bf16 [32][1024][32]
constexpr size_t OFF_ROUT   = OFF_WGU;   // bf16 [4096][1024] overlay

__device__ __forceinline__ unsigned short f2bf(float f) {
  union { float f; uint32_t u; } v; v.f = f;
  uint32_t r = (v.u + 0x7FFFu + ((v.u >> 16) & 1u)) >> 16;
  return (unsigned short)r;
}
__device__ __forceinline__ float bfu2f(uint32_t u) {
  union { uint32_t u; float f; } v; v.u = u << 16; return v.f;
}
__device__ __forceinline__ bf16x8 as_bf16x8(ushort8 s) {
  union { ushort8 s; bf16x8 b; } u; u.s = s; return u.b;
}
__device__ __forceinline__ float silu(float g) { return g / (1.f + __expf(-g)); }

__device__ __forceinline__ void glds16(const unsigned short* g, unsigned short* l) {
  __builtin_amdgcn_global_load_lds(
      (const __attribute__((address_space(1))) unsigned int*)g,
      (__attribute__((address_space(3))) unsigned int*)l, 16, 0, 0);
}

// 4 glds/wave/stage, 3 stages in flight. Barrier waits only the OLDEST
// in-flight stage (vmcnt(8) leaves the 2 newer stages' 8 loads in flight).
// lgkmcnt(0): this wave's ds_reads of the previous compute are in registers
// before any buffer can be overwritten.
#define PIPE_BARRIER8() asm volatile("s_waitcnt vmcnt(8) lgkmcnt(0)\ns_barrier" ::: "memory")
#define PIPE_BARRIER4() asm volatile("s_waitcnt vmcnt(4) lgkmcnt(0)\ns_barrier" ::: "memory")
#define PIPE_BARRIER0() asm volatile("s_waitcnt vmcnt(0) lgkmcnt(0)\ns_barrier" ::: "memory")

// -------------------------- init: zero expert counts -----------------------
__global__ void init_kernel(int* counts) {
  if (threadIdx.x < NEXP) counts[threadIdx.x] = 0;
}

// ------------- router (fp32, one wave/token) + fused x->bf16 write ---------
__global__ __launch_bounds__(64) void router_kernel(
    const float* __restrict__ x, const float* __restrict__ rw,
    int* counts, int* list, float* wt, int* tIdx,
    unsigned short* __restrict__ Xb) {
  const int t = blockIdx.x, l = threadIdx.x;
  float xv[16];
#pragma unroll
  for (int j = 0; j < 16; j++) xv[j] = x[t * HID + j * 64 + l];
#pragma unroll
  for (int j = 0; j < 16; j++) Xb[t * HID + j * 64 + l] = f2bf(xv[j]);
  float p[NEXP];
#pragma unroll
  for (int e = 0; e < NEXP; e++) {
    float s = 0.f;
#pragma unroll
    for (int j = 0; j < 16; j++) s += xv[j] * rw[e * HID + j * 64 + l];
#pragma unroll
    for (int off = 32; off > 0; off >>= 1) s += __shfl_xor(s, off);
    p[e] = s;
  }
  float mx = p[0];
#pragma unroll
  for (int e = 1; e < NEXP; e++) mx = fmaxf(mx, p[e]);
  int idx[TOPK]; float w4[TOPK]; float wsum = 0.f; unsigned used = 0u;
#pragma unroll
  for (int k = 0; k < TOPK; k++) {
    float bv = -1e30f; int bi = 0;
#pragma unroll
    for (int e = 0; e < NEXP; e++)
      if (!((used >> e) & 1u) && p[e] > bv) { bv = p[e]; bi = e; }
    used |= 1u << bi;
    idx[k] = bi;
    w4[k] = __expf(p[bi] - mx);
    wsum += w4[k];
  }
  const float inv = 1.f / wsum;
  if (l < TOPK) {
    const int e = idx[l];
    const int pos = atomicAdd(&counts[e], 1);
    list[e * 1024 + pos] = t;
    wt[e * 1024 + pos]   = w4[l] * inv;
    tIdx[t * TOPK + l]   = (e << 10) | pos;
  }
}

// -------- pack_all: fp32 [K][N] weights -> bf16 k-panels [K/32][Nj][32] ----
// Interleaved (gate/up): packed j for col c = 32*(c>>4)+(c&15) (+16 for up).
__global__ __launch_bounds__(256) void pack_all_kernel(
    const float* __restrict__ Wg, const float* __restrict__ Wu,
    const float* __restrict__ Wd, const float* __restrict__ Wsgu,
    const float* __restrict__ Wsd,
    unsigned short* __restrict__ WGUp, unsigned short* __restrict__ WDp,
    unsigned short* __restrict__ WSGUp, unsigned short* __restrict__ WSDp) {
  const int bid = blockIdx.x;
  const float* src; unsigned short* dst; int C, Nj, kp0, r0, c0, jbase, ilv;
  if (bid < 2048) {                      // Wg: [16][1024][512]
    const int e = bid >> 7, loc = bid & 127, kt = loc >> 3, nt = loc & 7;
    src = Wg + (size_t)e * HID * MINTER; dst = WGUp + (size_t)e * WGU_E;
    C = MINTER; Nj = 1024; kp0 = 2 * kt; r0 = 64 * kt; c0 = 64 * nt;
    jbase = 128 * nt; ilv = 1;
  } else if (bid < 4096) {               // Wu
    const int e = (bid - 2048) >> 7, loc = bid & 127, kt = loc >> 3, nt = loc & 7;
    src = Wu + (size_t)e * HID * MINTER; dst = WGUp + (size_t)e * WGU_E;
    C = MINTER; Nj = 1024; kp0 = 2 * kt; r0 = 64 * kt; c0 = 64 * nt;
    jbase = 128 * nt + 16; ilv = 1;
  } else if (bid < 6144) {               // Wd: [16][512][1024]
    const int e = (bid - 4096) >> 7, loc = bid & 127, kt = loc >> 4, nt = loc & 15;
    src = Wd + (size_t)e * MINTER * HID; dst = WDp + (size_t)e * WD_E;
    C = HID; Nj = 1024; kp0 = 2 * kt; r0 = 64 * kt; c0 = 64 * nt;
    jbase = 64 * nt; ilv = 0;
  } else if (bid < 6656) {               // Wsgu: [1024][2048]
    const int loc = bid - 6144, kt = loc >> 5, nt = loc & 31;
    src = Wsgu; dst = WSGUp;
    C = 2048; Nj = 2048; kp0 = 2 * kt; r0 = 64 * kt; c0 = 64 * nt;
    const int isU = (nt >= 16), ntc = nt & 15;
    jbase = 128 * ntc + 16 * isU; ilv = 1;
  } else {                               // Wsd: [1024][1024]
    const int loc = bid - 6656, kt = loc >> 4, nt = loc & 15;
    src = Wsd; dst = WSDp;
    C = HID; Nj = 1024; kp0 = 2 * kt; r0 = 64 * kt; c0 = 64 * nt;
    jbase = 64 * nt; ilv = 0;
  }
  __shared__ float tile[64][65];
  const int t = threadIdx.x;
  {
    const int r = t >> 4, c4 = (t & 15) * 4;
#pragma unroll
    for (int p = 0; p < 4; p++) {
      const int rr = p * 16 + r;
      const float4 v = *(const float4*)(src + (size_t)(r0 + rr) * C + c0 + c4);
      tile[rr][c4 + 0] = v.x; tile[rr][c4 + 1] = v.y;
      tile[rr][c4 + 2] = v.z; tile[rr][c4 + 3] = v.w;
    }
  }
  __syncthreads();
  {
    const int n = t >> 2, k8 = (t & 3) * 8;
    const int j = jbase + (ilv ? (32 * (n >> 4) + (n & 15)) : n);
#pragma unroll
    for (int h = 0; h < 2; h++) {
      const int k = 32 * h + k8;
      union { unsigned short u[8]; ushort8 v; } pk;
#pragma unroll
      for (int i = 0; i < 8; i++) pk.u[i] = f2bf(tile[k + i][n]);
      *(ushort8*)(dst + ((size_t)(kp0 + h) * Nj + j) * 32 + k8) = pk.v;
    }
  }
}

// ---------------------------------------------------------------------------
// Phase 1: gate/up. Block 64m x 64j, 2 waves (wn = w: j-half of 32 = 16G+16U),
// BK=32. Wave: 4 A-frags (full 64m), 2 B-frags, 8 MFMA per step.
// 4-stage pipeline, vmcnt(8) barriers. LDS 32 KB -> 5 blocks/CU.
// ---------------------------------------------------------------------------
__global__ __launch_bounds__(128, 3) void phase1_kernel(
    const unsigned short* __restrict__ Xb,
    const unsigned short* __restrict__ WGUp,
    const unsigned short* __restrict__ WSGUp,
    const int* __restrict__ counts, const int* __restrict__ list,
    const float* __restrict__ wt,
    unsigned short* __restrict__ Hr,   // [16][4096][32]
    unsigned short* __restrict__ Hs) { // [32][1024][32]
  const int z = blockIdx.z, x = blockIdx.x, y = blockIdx.y;
  const bool routed = (z < NEXP);
  int cnt = 0, base = 0;
  if (routed) {
    if (x >= 16) return;               // routed Nj=1024 -> 16 x-tiles of 64
    cnt = counts[z];
    if (y * 64 >= cnt) return;
#pragma unroll
    for (int i = 0; i < NEXP; i++) base += (i < z) ? counts[i] : 0;
  }
  __shared__ __align__(16) unsigned short sA[4][64 * 32];
  __shared__ __align__(16) unsigned short sB[4][64 * 32];
  const int tid = threadIdx.x, w = tid >> 6, l = tid & 63;
  const int wn = w, m0 = y * 64;
  const int swz = ((l & 3) ^ ((l >> 3) & 3)) * 8;
  const int Nj = routed ? 1024 : 2048;

  // A staging: wave w covers sA rows [32w,32w+32) as 2 glds of 16 rows
  const unsigned short* aS[2];
#pragma unroll
  for (int ii = 0; ii < 2; ii++) {
    const int r = 32 * w + 16 * ii + (l >> 2);
    const unsigned short* row = routed
        ? Xb + (size_t)list[z * 1024 + min(m0 + r, cnt - 1)] * HID
        : Xb + (size_t)(m0 + r) * HID;
    aS[ii] = row + swz;
  }
  // B staging: wave w covers sB rows [32w,32w+32) as 2 glds of 16 rows
  const unsigned short* pan = routed ? WGUp + (size_t)z * WGU_E : WSGUp;
  const unsigned short* bS[2];
#pragma unroll
  for (int ii = 0; ii < 2; ii++)
    bS[ii] = pan + ((size_t)(x * 64 + 32 * w + 16 * ii + (l >> 2))) * 32 + swz;
  const size_t bStep = (size_t)Nj * 32;

  const int rsw = ((l >> 4) ^ (((l & 15) >> 1) & 3)) * 8;
  int aOff[4], bOff[2];
#pragma unroll
  for (int i = 0; i < 4; i++) aOff[i] = (16 * i + (l & 15)) * 32 + rsw;
#pragma unroll
  for (int jt = 0; jt < 2; jt++) bOff[jt] = (32 * wn + 16 * jt + (l & 15)) * 32 + rsw;

  f32x4 acc[4][2];
#pragma unroll
  for (int i = 0; i < 4; i++)
#pragma unroll
    for (int jt = 0; jt < 2; jt++) acc[i][jt] = (f32x4){0.f, 0.f, 0.f, 0.f};

  auto stage = [&](int s, int b) {
    glds16(aS[0] + s * 32, &sA[b][(32 * w) * 32]);
    glds16(aS[1] + s * 32, &sA[b][(32 * w + 16) * 32]);
    glds16(bS[0] + s * bStep, &sB[b][(32 * w) * 32]);
    glds16(bS[1] + s * bStep, &sB[b][(32 * w + 16) * 32]);
  };

  const int steps = HID / 32;   // 32
  stage(0, 0); stage(1, 1); stage(2, 2);
#pragma unroll 1
  for (int s = 0; s < steps; s++) {
    const int cb = s & 3;
    if (s + 3 < steps)       { PIPE_BARRIER8(); stage(s + 3, (s + 3) & 3); }
    else if (s + 3 == steps) { PIPE_BARRIER8(); }
    else if (s + 2 == steps) { PIPE_BARRIER4(); }
    else                     { PIPE_BARRIER0(); }
    const unsigned short* A = &sA[cb][0];
    const unsigned short* B = &sB[cb][0];
    bf16x8 af[4], bfr[2];
#pragma unroll
    for (int i = 0; i < 4; i++) af[i] = as_bf16x8(*(const ushort8*)(A + aOff[i]));
#pragma unroll
    for (int jt = 0; jt < 2; jt++) bfr[jt] = as_bf16x8(*(const ushort8*)(B + bOff[jt]));
#pragma unroll
    for (int jt = 0; jt < 2; jt++)
#pragma unroll
      for (int i = 0; i < 4; i++)
        acc[i][jt] = __builtin_amdgcn_mfma_f32_16x16x32_bf16(af[i], bfr[jt], acc[i][jt], 0, 0, 0);
  }

  // epilogue: D col=lane&15, row=(lane>>4)*4+reg; jt=0 -> G, jt=1 -> U.
  // I-col c = 32x + 16wn + (lane&15); panel = x, in-panel col = 16wn+(lane&15).
  const int rl = (l >> 4) * 4, pc = 16 * wn + (l & 15);
#pragma unroll
  for (int i = 0; i < 4; i++)
#pragma unroll
    for (int r = 0; r < 4; r++) {
      const int grow = m0 + 16 * i + rl + r;
      const float g = acc[i][0][r], u = acc[i][1][r];
      if (routed) {
        if (grow < cnt) {
          const float h = silu(g) * u * wt[z * 1024 + grow];
          Hr[((size_t)x * 4096 + base + grow) * 32 + pc] = f2bf(h);
        }
      } else {
        const float h = silu(g) * u;
        Hs[((size_t)x * 1024 + grow) * 32 + pc] = f2bf(h);
      }
    }
}

// ---------------------------------------------------------------------------
// Phase 2: down-proj. Block 64m x 64n, 2 waves, BK=32; same 4-stage pipeline.
// Routed (z<16): K=512 -> bf16 Rout; shared (z==16): K=1024 -> fp32 out.
// ---------------------------------------------------------------------------
__global__ __launch_bounds__(128, 3) void phase2_kernel(
    const unsigned short* __restrict__ Hr, const unsigned short* __restrict__ Hs,
    const unsigned short* __restrict__ WDp, const unsigned short* __restrict__ WSDp,
    const int* __restrict__ counts,
    unsigned short* __restrict__ Rout,   // bf16 [4096][1024]
    float* __restrict__ out) {           // fp32 [1024][1024]
  const int z = blockIdx.z, x = blockIdx.x, y = blockIdx.y;
  const bool routed = (z < NEXP);
  int cnt = 0, base = 0, steps;
  if (routed) {
    cnt = counts[z];
    if (y * 64 >= cnt) return;
#pragma unroll
    for (int i = 0; i < NEXP; i++) base += (i < z) ? counts[i] : 0;
    steps = MINTER / 32;   // 16
  } else {
    steps = SINTER / 32;   // 32
  }
  __shared__ __align__(16) unsigned short sA[4][64 * 32];
  __shared__ __align__(16) unsigned short sB[4][64 * 32];
  const int tid = threadIdx.x, w = tid >> 6, l = tid & 63;
  const int wn = w, m0 = y * 64;
  const int swz = ((l & 3) ^ ((l >> 3) & 3)) * 8;
  const size_t aStep = (size_t)(routed ? 4096 : 1024) * 32;

  const unsigned short* aS[2];
#pragma unroll
  for (int ii = 0; ii < 2; ii++) {
    const int r = 32 * w + 16 * ii + (l >> 2);
    const int R = routed ? (base + min(m0 + r, cnt - 1)) : (m0 + r);
    aS[ii] = (routed ? Hr : Hs) + (size_t)R * 32 + swz;
  }
  const unsigned short* pan = routed ? WDp + (size_t)z * WD_E : WSDp;
  const unsigned short* bS[2];
#pragma unroll
  for (int ii = 0; ii < 2; ii++)
    bS[ii] = pan + ((size_t)(x * 64 + 32 * w + 16 * ii + (l >> 2))) * 32 + swz;
  const size_t bStep = (size_t)1024 * 32;

  const int rsw = ((l >> 4) ^ (((l & 15) >> 1) & 3)) * 8;
  int aOff[4], bOff[2];
#pragma unroll
  for (int i = 0; i < 4; i++) aOff[i] = (16 * i + (l & 15)) * 32 + rsw;
#pragma unroll
  for (int jt = 0; jt < 2; jt++) bOff[jt] = (32 * wn + 16 * jt + (l & 15)) * 32 + rsw;

  f32x4 acc[4][2];
#pragma unroll
  for (int i = 0; i < 4; i++)
#pragma unroll
    for (int jt = 0; jt < 2; jt++) acc[i][jt] = (f32x4){0.f, 0.f, 0.f, 0.f};

  auto stage = [&](int s, int b) {
    glds16(aS[0] + s * aStep, &sA[b][(32 * w) * 32]);
    glds16(aS[1] + s * aStep, &sA[b][(32 * w + 16) * 32]);
    glds16(bS[0] + s * bStep, &sB[b][(32 * w) * 32]);
    glds16(bS[1] + s * bStep, &sB[b][(32 * w + 16) * 32]);
  };

  stage(0, 0); stage(1, 1); stage(2, 2);
#pragma unroll 1
  for (int s = 0; s < steps; s++) {
    const int cb = s & 3;
    if (s + 3 < steps)       { PIPE_BARRIER8(); stage(s + 3, (s + 3) & 3); }
    else if (s + 3 == steps) { PIPE_BARRIER8(); }
    else if (s + 2 == steps) { PIPE_BARRIER4(); }
    else                     { PIPE_BARRIER0(); }
    const unsigned short* A = &sA[cb][0];
    const unsigned short* B = &sB[cb][0];
    bf16x8 af[4], bfr[2];
#pragma unroll
    for (int i = 0; i < 4; i++) af[i] = as_bf16x8(*(const ushort8*)(A + aOff[i]));
#pragma unroll
    for (int jt = 0; jt < 2; jt++) bfr[jt] = as_bf16x8(*(const ushort8*)(B + bOff[jt]));
#pragma unroll
    for (int jt = 0; jt < 2; jt++)
#pragma unroll
      for (int i = 0; i < 4; i++)
        acc[i][jt] = __builtin_amdgcn_mfma_f32_16x16x32_bf16(af[i], bfr[jt], acc[i][jt], 0, 0, 0);
  }

  const int rl = (l >> 4) * 4;
#pragma unroll
  for (int i = 0; i < 4; i++)
#pragma unroll
    for (int r = 0; r < 4; r++) {
      const int grow = m0 + 16 * i + rl + r;
#pragma unroll
      for (int jt = 0; jt < 2; jt++) {
        const int col = 64 * x + 32 * wn + 16 * jt + (l & 15);
        if (routed) {
          if (grow < cnt)
            Rout[(size_t)(base + grow) * HID + col] = f2bf(acc[i][jt][r]);
        } else {
          out[(size_t)grow * HID + col] = acc[i][jt][r];
        }
      }
    }
}

// ------------- combine: out[t] += sum_k Rout[base[e_k]+pos_k] (bf16) -------
__global__ __launch_bounds__(256) void combine_kernel(
    const unsigned short* __restrict__ Rout, const int* __restrict__ counts,
    const int* __restrict__ tIdx, float* __restrict__ out) {
  __shared__ int sb[NEXP];
  if (threadIdx.x == 0) {
    int s = 0;
#pragma unroll
    for (int e = 0; e < NEXP; e++) { sb[e] = s; s += counts[e]; }
  }
  __syncthreads();
  const int t = blockIdx.x, c4 = threadIdx.x * 4;
  float4 o = *(const float4*)(out + (size_t)t * HID + c4);
#pragma unroll
  for (int k = 0; k < TOPK; k++) {
    const int v = tIdx[t * TOPK + k];
    const int row = sb[v >> 10] + (v & 1023);
    const uint2 rv = *(const uint2*)(Rout + (size_t)row * HID + c4);
    o.x += bfu2f(rv.x & 0xffffu); o.y += bfu2f(rv.x >> 16);
    o.z += bfu2f(rv.y & 0xffffu); o.w += bfu2f(rv.y >> 16);
  }
  *(float4*)(out + (size_t)t * HID + c4) = o;
}

// ---------------------------------------------------------------------------
extern "C" void kernel_launch(void* const* d_in, const int* in_sizes, int n_in,
                              void* d_out, int out_size, void* d_ws, size_t ws_size,
                              hipStream_t stream) {
  const float* x      = (const float*)d_in[0];
  const float* rw     = (const float*)d_in[1];
  const float* w_gate = (const float*)d_in[2];
  const float* w_up   = (const float*)d_in[3];
  const float* w_down = (const float*)d_in[4];
  const float* ws_gu  = (const float*)d_in[5];
  const float* ws_dn  = (const float*)d_in[6];
  float* out = (float*)d_out;
  char* ws = (char*)d_ws;

  int*   counts = (int*)  (ws + OFF_COUNTS);
  int*   list   = (int*)  (ws + OFF_LIST);
  float* wtbuf  = (float*)(ws + OFF_WT);
  int*   tIdx   = (int*)  (ws + OFF_TIDX);
  unsigned short* Xb    = (unsigned short*)(ws + OFF_XB);
  unsigned short* Hr    = (unsigned short*)(ws + OFF_HR);
  unsigned short* Hs    = (unsigned short*)(ws + OFF_HS);
  unsigned short* WGUp  = (unsigned short*)(ws + OFF_WGU);
  unsigned short* WDp   = (unsigned short*)(ws + OFF_WD);
  unsigned short* WSGUp = (unsigned short*)(ws + OFF_WSGU);
  unsigned short* WSDp  = (unsigned short*)(ws + OFF_WSD);
  unsigned short* Rout  = (unsigned short*)(ws + OFF_ROUT);

  init_kernel<<<1, 64, 0, stream>>>(counts);
  router_kernel<<<T_TOK, 64, 0, stream>>>(x, rw, counts, list, wtbuf, tIdx, Xb);
  pack_all_kernel<<<6912, 256, 0, stream>>>(
      w_gate, w_up, w_down, ws_gu, ws_dn, WGUp, WDp, WSGUp, WSDp);
  phase1_kernel<<<dim3(32, 16, 17), 128, 0, stream>>>(
      Xb, WGUp, WSGUp, counts, list, wtbuf, Hr, Hs);
  phase2_kernel<<<dim3(16, 16, 17), 128, 0, stream>>>(
      Hr, Hs, WDp, WSDp, counts, Rout, out);
  combine_kernel<<<T_TOK, 256, 0, stream>>>(Rout, counts, tIdx, out);
  (void)in_sizes; (void)n_in; (void)out_size; (void)ws_size;
}

// Round 2
// 249.062 us; speedup vs baseline: 1.0495x; 1.0495x over previous
//
#include <hip/hip_runtime.h>
#include <stdint.h>

// ---------------------------------------------------------------------------
// BailingMoE block: T=1024, H=1024, E=16, top-4, I=512 routed, Is=1024 shared
// R9: arithmetic-intensity fix. R7/R8 both ~61us with step time ~2250cy --
// invariant was LDS-staged bytes (no B cross-wave reuse at 64-col tiles).
// Re-tiled to 128x128 block / 4 waves / wave 64x64 (4x4 frags, 16 MFMA/step),
// BK=32, 3-stage pipeline, vmcnt(4) barriers. Staged traffic halves
// (390->196MB phase1), per-step compute doubles. LDS 48KB -> 3 blocks/CU.
// ---------------------------------------------------------------------------

typedef __attribute__((ext_vector_type(8))) unsigned short ushort8;
typedef __attribute__((ext_vector_type(4))) float f32x4;
typedef __attribute__((ext_vector_type(8))) __bf16 bf16x8;

#define T_TOK 1024
#define HID   1024
#define NEXP  16
#define TOPK  4
#define MINTER 512
#define SINTER 1024

constexpr size_t WGU_E = 32 * 1024 * 32;   // per-expert gate/up panels
constexpr size_t WD_E  = 16 * 1024 * 32;   // per-expert down panels

constexpr size_t OFF_COUNTS = 0;
constexpr size_t OFF_LIST   = 1024;
constexpr size_t OFF_WT     = OFF_LIST  + 65536;
constexpr size_t OFF_TIDX   = OFF_WT    + 65536;
constexpr size_t OFF_XB     = OFF_TIDX  + 65536;               // bf16 [1024][1024]
constexpr size_t OFF_HR     = OFF_XB    + 2097152;             // bf16 [16][4096][32]
constexpr size_t OFF_HS     = OFF_HR    + 4194304;             // bf16 [32][1024][32]
constexpr size_t OFF_WGU    = OFF_HS    + 2097152;             // bf16 [16]xWGU_E
constexpr size_t OFF_WD     = OFF_WGU   + 33554432;            // bf16 [16]xWD_E
constexpr size_t OFF_WSGU   = OFF_WD    + 16777216;            // bf16 [32][2048][32]
constexpr size_t OFF_WSD    = OFF_WSGU  + 4194304;             // bf16 [32][1024][32]
constexpr size_t OFF_ROUT   = OFF_WGU;   // bf16 [4096][1024] overlay

__device__ __forceinline__ unsigned short f2bf(float f) {
  union { float f; uint32_t u; } v; v.f = f;
  uint32_t r = (v.u + 0x7FFFu + ((v.u >> 16) & 1u)) >> 16;
  return (unsigned short)r;
}
__device__ __forceinline__ float bfu2f(uint32_t u) {
  union { uint32_t u; float f; } v; v.u = u << 16; return v.f;
}
__device__ __forceinline__ bf16x8 as_bf16x8(ushort8 s) {
  union { ushort8 s; bf16x8 b; } u; u.s = s; return u.b;
}
__device__ __forceinline__ float silu(float g) { return g / (1.f + __expf(-g)); }

__device__ __forceinline__ void glds16(const unsigned short* g, unsigned short* l) {
  __builtin_amdgcn_global_load_lds(
      (const __attribute__((address_space(1))) unsigned int*)g,
      (__attribute__((address_space(3))) unsigned int*)l, 16, 0, 0);
}

// 4 glds/wave/stage, 2 stages in flight at the wait. vmcnt(4) drains only the
// OLDEST stage (the newer stage's 4 loads stay in flight across the barrier).
// lgkmcnt(0): this wave's ds_reads of the previous step are in registers
// before any buffer can be overwritten. vmcnt precedes s_barrier so ALL
// waves' oldest-stage loads are complete once every wave passes the barrier.
#define PIPE_BARRIER4() asm volatile("s_waitcnt vmcnt(4) lgkmcnt(0)\ns_barrier" ::: "memory")
#define PIPE_BARRIER0() asm volatile("s_waitcnt vmcnt(0) lgkmcnt(0)\ns_barrier" ::: "memory")

// -------------------------- init: zero expert counts -----------------------
__global__ void init_kernel(int* counts) {
  if (threadIdx.x < NEXP) counts[threadIdx.x] = 0;
}

// ------------- router (fp32, one wave/token) + fused x->bf16 write ---------
__global__ __launch_bounds__(64) void router_kernel(
    const float* __restrict__ x, const float* __restrict__ rw,
    int* counts, int* list, float* wt, int* tIdx,
    unsigned short* __restrict__ Xb) {
  const int t = blockIdx.x, l = threadIdx.x;
  float xv[16];
#pragma unroll
  for (int j = 0; j < 16; j++) xv[j] = x[t * HID + j * 64 + l];
#pragma unroll
  for (int j = 0; j < 16; j++) Xb[t * HID + j * 64 + l] = f2bf(xv[j]);
  float p[NEXP];
#pragma unroll
  for (int e = 0; e < NEXP; e++) {
    float s = 0.f;
#pragma unroll
    for (int j = 0; j < 16; j++) s += xv[j] * rw[e * HID + j * 64 + l];
#pragma unroll
    for (int off = 32; off > 0; off >>= 1) s += __shfl_xor(s, off);
    p[e] = s;
  }
  float mx = p[0];
#pragma unroll
  for (int e = 1; e < NEXP; e++) mx = fmaxf(mx, p[e]);
  int idx[TOPK]; float w4[TOPK]; float wsum = 0.f; unsigned used = 0u;
#pragma unroll
  for (int k = 0; k < TOPK; k++) {
    float bv = -1e30f; int bi = 0;
#pragma unroll
    for (int e = 0; e < NEXP; e++)
      if (!((used >> e) & 1u) && p[e] > bv) { bv = p[e]; bi = e; }
    used |= 1u << bi;
    idx[k] = bi;
    w4[k] = __expf(p[bi] - mx);
    wsum += w4[k];
  }
  const float inv = 1.f / wsum;
  if (l < TOPK) {
    const int e = idx[l];
    const int pos = atomicAdd(&counts[e], 1);
    list[e * 1024 + pos] = t;
    wt[e * 1024 + pos]   = w4[l] * inv;
    tIdx[t * TOPK + l]   = (e << 10) | pos;
  }
}

// -------- pack_all: fp32 [K][N] weights -> bf16 k-panels [K/32][Nj][32] ----
// Interleaved (gate/up): packed j for col c = 32*(c>>4)+(c&15) (+16 for up).
__global__ __launch_bounds__(256) void pack_all_kernel(
    const float* __restrict__ Wg, const float* __restrict__ Wu,
    const float* __restrict__ Wd, const float* __restrict__ Wsgu,
    const float* __restrict__ Wsd,
    unsigned short* __restrict__ WGUp, unsigned short* __restrict__ WDp,
    unsigned short* __restrict__ WSGUp, unsigned short* __restrict__ WSDp) {
  const int bid = blockIdx.x;
  const float* src; unsigned short* dst; int C, Nj, kp0, r0, c0, jbase, ilv;
  if (bid < 2048) {                      // Wg: [16][1024][512]
    const int e = bid >> 7, loc = bid & 127, kt = loc >> 3, nt = loc & 7;
    src = Wg + (size_t)e * HID * MINTER; dst = WGUp + (size_t)e * WGU_E;
    C = MINTER; Nj = 1024; kp0 = 2 * kt; r0 = 64 * kt; c0 = 64 * nt;
    jbase = 128 * nt; ilv = 1;
  } else if (bid < 4096) {               // Wu
    const int e = (bid - 2048) >> 7, loc = bid & 127, kt = loc >> 3, nt = loc & 7;
    src = Wu + (size_t)e * HID * MINTER; dst = WGUp + (size_t)e * WGU_E;
    C = MINTER; Nj = 1024; kp0 = 2 * kt; r0 = 64 * kt; c0 = 64 * nt;
    jbase = 128 * nt + 16; ilv = 1;
  } else if (bid < 6144) {               // Wd: [16][512][1024]
    const int e = (bid - 4096) >> 7, loc = bid & 127, kt = loc >> 4, nt = loc & 15;
    src = Wd + (size_t)e * MINTER * HID; dst = WDp + (size_t)e * WD_E;
    C = HID; Nj = 1024; kp0 = 2 * kt; r0 = 64 * kt; c0 = 64 * nt;
    jbase = 64 * nt; ilv = 0;
  } else if (bid < 6656) {               // Wsgu: [1024][2048]
    const int loc = bid - 6144, kt = loc >> 5, nt = loc & 31;
    src = Wsgu; dst = WSGUp;
    C = 2048; Nj = 2048; kp0 = 2 * kt; r0 = 64 * kt; c0 = 64 * nt;
    const int isU = (nt >= 16), ntc = nt & 15;
    jbase = 128 * ntc + 16 * isU; ilv = 1;
  } else {                               // Wsd: [1024][1024]
    const int loc = bid - 6656, kt = loc >> 4, nt = loc & 15;
    src = Wsd; dst = WSDp;
    C = HID; Nj = 1024; kp0 = 2 * kt; r0 = 64 * kt; c0 = 64 * nt;
    jbase = 64 * nt; ilv = 0;
  }
  __shared__ float tile[64][65];
  const int t = threadIdx.x;
  {
    const int r = t >> 4, c4 = (t & 15) * 4;
#pragma unroll
    for (int p = 0; p < 4; p++) {
      const int rr = p * 16 + r;
      const float4 v = *(const float4*)(src + (size_t)(r0 + rr) * C + c0 + c4);
      tile[rr][c4 + 0] = v.x; tile[rr][c4 + 1] = v.y;
      tile[rr][c4 + 2] = v.z; tile[rr][c4 + 3] = v.w;
    }
  }
  __syncthreads();
  {
    const int n = t >> 2, k8 = (t & 3) * 8;
    const int j = jbase + (ilv ? (32 * (n >> 4) + (n & 15)) : n);
#pragma unroll
    for (int h = 0; h < 2; h++) {
      const int k = 32 * h + k8;
      union { unsigned short u[8]; ushort8 v; } pk;
#pragma unroll
      for (int i = 0; i < 8; i++) pk.u[i] = f2bf(tile[k + i][n]);
      *(ushort8*)(dst + ((size_t)(kp0 + h) * Nj + j) * 32 + k8) = pk.v;
    }
  }
}

// ---------------------------------------------------------------------------
// Phase 1: gate/up. Block 128m x 128j, 4 waves (wm=w>>1, wn=w&1), wave tile
// 64m x 64j = 4x4 frags, 16 MFMA/step, BK=32. 3-stage pipeline, vmcnt(4).
// j interleave: 32-col blocks are [16G][16U]; wave's jt pairs (0,1),(2,3)
// are (G,U) for consecutive 16-wide I-col groups. LDS 48KB -> 3 blocks/CU.
// ---------------------------------------------------------------------------
__global__ __launch_bounds__(256, 3) void phase1_kernel(
    const unsigned short* __restrict__ Xb,
    const unsigned short* __restrict__ WGUp,
    const unsigned short* __restrict__ WSGUp,
    const int* __restrict__ counts, const int* __restrict__ list,
    const float* __restrict__ wt,
    unsigned short* __restrict__ Hr,   // [16][4096][32]
    unsigned short* __restrict__ Hs) { // [32][1024][32]
  const int z = blockIdx.z, x = blockIdx.x, y = blockIdx.y;
  const bool routed = (z < NEXP);
  int cnt = 0, base = 0;
  if (routed) {
    if (x >= 8) return;                // routed Nj=1024 -> 8 x-tiles of 128
    cnt = counts[z];
    if (y * 128 >= cnt) return;
#pragma unroll
    for (int i = 0; i < NEXP; i++) base += (i < z) ? counts[i] : 0;
  }
  __shared__ __align__(16) unsigned short sA[3][128 * 32];
  __shared__ __align__(16) unsigned short sB[3][128 * 32];
  const int tid = threadIdx.x, w = tid >> 6, l = tid & 63;
  const int wm = w >> 1, wn = w & 1, m0 = y * 128;
  const int swz = ((l & 3) ^ ((l >> 3) & 3)) * 8;
  const int Nj = routed ? 1024 : 2048;

  // A staging: wave w covers sA rows [32w,32w+32) as 2 glds of 16 rows
  const unsigned short* aS[2];
#pragma unroll
  for (int ii = 0; ii < 2; ii++) {
    const int r = 32 * w + 16 * ii + (l >> 2);
    const unsigned short* row = routed
        ? Xb + (size_t)list[z * 1024 + min(m0 + r, cnt - 1)] * HID
        : Xb + (size_t)(m0 + r) * HID;
    aS[ii] = row + swz;
  }
  // B staging: wave w covers sB rows [32w,32w+32) as 2 glds of 16 rows
  const unsigned short* pan = routed ? WGUp + (size_t)z * WGU_E : WSGUp;
  const unsigned short* bS[2];
#pragma unroll
  for (int ii = 0; ii < 2; ii++)
    bS[ii] = pan + ((size_t)(x * 128 + 32 * w + 16 * ii + (l >> 2))) * 32 + swz;
  const size_t bStep = (size_t)Nj * 32;

  const int rsw = ((l >> 4) ^ (((l & 15) >> 1) & 3)) * 8;
  int aOff[4], bOff[4];
#pragma unroll
  for (int i = 0; i < 4; i++) aOff[i] = (64 * wm + 16 * i + (l & 15)) * 32 + rsw;
#pragma unroll
  for (int jt = 0; jt < 4; jt++) bOff[jt] = (64 * wn + 16 * jt + (l & 15)) * 32 + rsw;

  f32x4 acc[4][4];
#pragma unroll
  for (int i = 0; i < 4; i++)
#pragma unroll
    for (int jt = 0; jt < 4; jt++) acc[i][jt] = (f32x4){0.f, 0.f, 0.f, 0.f};

  auto stage = [&](int s, int b) {
    glds16(aS[0] + s * 32, &sA[b][(32 * w) * 32]);
    glds16(aS[1] + s * 32, &sA[b][(32 * w + 16) * 32]);
    glds16(bS[0] + s * bStep, &sB[b][(32 * w) * 32]);
    glds16(bS[1] + s * bStep, &sB[b][(32 * w + 16) * 32]);
  };

  const int steps = HID / 32;   // 32
  stage(0, 0); stage(1, 1);
#pragma unroll 1
  for (int s = 0; s < steps; s++) {
    const int cb = s % 3;
    if (s + 2 < steps)      { PIPE_BARRIER4(); stage(s + 2, (s + 2) % 3); }
    else if (s + 1 < steps) { PIPE_BARRIER4(); }
    else                    { PIPE_BARRIER0(); }
    const unsigned short* A = &sA[cb][0];
    const unsigned short* B = &sB[cb][0];
    bf16x8 af[4], bfr[4];
#pragma unroll
    for (int i = 0; i < 4; i++) af[i] = as_bf16x8(*(const ushort8*)(A + aOff[i]));
#pragma unroll
    for (int jt = 0; jt < 4; jt++) bfr[jt] = as_bf16x8(*(const ushort8*)(B + bOff[jt]));
#pragma unroll
    for (int jt = 0; jt < 4; jt++)
#pragma unroll
      for (int i = 0; i < 4; i++)
        acc[i][jt] = __builtin_amdgcn_mfma_f32_16x16x32_bf16(af[i], bfr[jt], acc[i][jt], 0, 0, 0);
  }

  // epilogue: D col=lane&15, row=(lane>>4)*4+reg. jt pair (2p,2p+1) = (G,U)
  // for H panel (2x+wn), in-panel col 16p+(l&15).
  const int rl = (l >> 4) * 4, cl = l & 15;
  const int panel = 2 * x + wn;
#pragma unroll
  for (int i = 0; i < 4; i++)
#pragma unroll
    for (int r = 0; r < 4; r++) {
      const int grow = m0 + 64 * wm + 16 * i + rl + r;
#pragma unroll
      for (int p = 0; p < 2; p++) {
        const float g = acc[i][2 * p][r], u = acc[i][2 * p + 1][r];
        if (routed) {
          if (grow < cnt) {
            const float h = silu(g) * u * wt[z * 1024 + grow];
            Hr[((size_t)panel * 4096 + base + grow) * 32 + 16 * p + cl] = f2bf(h);
          }
        } else {
          const float h = silu(g) * u;
          Hs[((size_t)panel * 1024 + grow) * 32 + 16 * p + cl] = f2bf(h);
        }
      }
    }
}

// ---------------------------------------------------------------------------
// Phase 2: down-proj. Block 128m x 128n, 4 waves, wave 64x64, BK=32; same
// 3-stage pipeline. Routed (z<16): K=512 -> bf16 Rout; shared: K=1024 -> fp32.
// ---------------------------------------------------------------------------
__global__ __launch_bounds__(256, 3) void phase2_kernel(
    const unsigned short* __restrict__ Hr, const unsigned short* __restrict__ Hs,
    const unsigned short* __restrict__ WDp, const unsigned short* __restrict__ WSDp,
    const int* __restrict__ counts,
    unsigned short* __restrict__ Rout,   // bf16 [4096][1024]
    float* __restrict__ out) {           // fp32 [1024][1024]
  const int z = blockIdx.z, x = blockIdx.x, y = blockIdx.y;
  const bool routed = (z < NEXP);
  int cnt = 0, base = 0, steps;
  if (routed) {
    cnt = counts[z];
    if (y * 128 >= cnt) return;
#pragma unroll
    for (int i = 0; i < NEXP; i++) base += (i < z) ? counts[i] : 0;
    steps = MINTER / 32;   // 16
  } else {
    steps = SINTER / 32;   // 32
  }
  __shared__ __align__(16) unsigned short sA[3][128 * 32];
  __shared__ __align__(16) unsigned short sB[3][128 * 32];
  const int tid = threadIdx.x, w = tid >> 6, l = tid & 63;
  const int wm = w >> 1, wn = w & 1, m0 = y * 128;
  const int swz = ((l & 3) ^ ((l >> 3) & 3)) * 8;
  const size_t aStep = (size_t)(routed ? 4096 : 1024) * 32;

  const unsigned short* aS[2];
#pragma unroll
  for (int ii = 0; ii < 2; ii++) {
    const int r = 32 * w + 16 * ii + (l >> 2);
    const int R = routed ? (base + min(m0 + r, cnt - 1)) : (m0 + r);
    aS[ii] = (routed ? Hr : Hs) + (size_t)R * 32 + swz;
  }
  const unsigned short* pan = routed ? WDp + (size_t)z * WD_E : WSDp;
  const unsigned short* bS[2];
#pragma unroll
  for (int ii = 0; ii < 2; ii++)
    bS[ii] = pan + ((size_t)(x * 128 + 32 * w + 16 * ii + (l >> 2))) * 32 + swz;
  const size_t bStep = (size_t)1024 * 32;

  const int rsw = ((l >> 4) ^ (((l & 15) >> 1) & 3)) * 8;
  int aOff[4], bOff[4];
#pragma unroll
  for (int i = 0; i < 4; i++) aOff[i] = (64 * wm + 16 * i + (l & 15)) * 32 + rsw;
#pragma unroll
  for (int jt = 0; jt < 4; jt++) bOff[jt] = (64 * wn + 16 * jt + (l & 15)) * 32 + rsw;

  f32x4 acc[4][4];
#pragma unroll
  for (int i = 0; i < 4; i++)
#pragma unroll
    for (int jt = 0; jt < 4; jt++) acc[i][jt] = (f32x4){0.f, 0.f, 0.f, 0.f};

  auto stage = [&](int s, int b) {
    glds16(aS[0] + s * aStep, &sA[b][(32 * w) * 32]);
    glds16(aS[1] + s * aStep, &sA[b][(32 * w + 16) * 32]);
    glds16(bS[0] + s * bStep, &sB[b][(32 * w) * 32]);
    glds16(bS[1] + s * bStep, &sB[b][(32 * w + 16) * 32]);
  };

  stage(0, 0); stage(1, 1);
#pragma unroll 1
  for (int s = 0; s < steps; s++) {
    const int cb = s % 3;
    if (s + 2 < steps)      { PIPE_BARRIER4(); stage(s + 2, (s + 2) % 3); }
    else if (s + 1 < steps) { PIPE_BARRIER4(); }
    else                    { PIPE_BARRIER0(); }
    const unsigned short* A = &sA[cb][0];
    const unsigned short* B = &sB[cb][0];
    bf16x8 af[4], bfr[4];
#pragma unroll
    for (int i = 0; i < 4; i++) af[i] = as_bf16x8(*(const ushort8*)(A + aOff[i]));
#pragma unroll
    for (int jt = 0; jt < 4; jt++) bfr[jt] = as_bf16x8(*(const ushort8*)(B + bOff[jt]));
#pragma unroll
    for (int jt = 0; jt < 4; jt++)
#pragma unroll
      for (int i = 0; i < 4; i++)
        acc[i][jt] = __builtin_amdgcn_mfma_f32_16x16x32_bf16(af[i], bfr[jt], acc[i][jt], 0, 0, 0);
  }

  const int rl = (l >> 4) * 4, cl = l & 15;
#pragma unroll
  for (int i = 0; i < 4; i++)
#pragma unroll
    for (int r = 0; r < 4; r++) {
      const int grow = m0 + 64 * wm + 16 * i + rl + r;
#pragma unroll
      for (int jt = 0; jt < 4; jt++) {
        const int col = 128 * x + 64 * wn + 16 * jt + cl;
        if (routed) {
          if (grow < cnt)
            Rout[(size_t)(base + grow) * HID + col] = f2bf(acc[i][jt][r]);
        } else {
          out[(size_t)grow * HID + col] = acc[i][jt][r];
        }
      }
    }
}

// ------------- combine: out[t] += sum_k Rout[base[e_k]+pos_k] (bf16) -------
__global__ __launch_bounds__(256) void combine_kernel(
    const unsigned short* __restrict__ Rout, const int* __restrict__ counts,
    const int* __restrict__ tIdx, float* __restrict__ out) {
  __shared__ int sb[NEXP];
  if (threadIdx.x == 0) {
    int s = 0;
#pragma unroll
    for (int e = 0; e < NEXP; e++) { sb[e] = s; s += counts[e]; }
  }
  __syncthreads();
  const int t = blockIdx.x, c4 = threadIdx.x * 4;
  float4 o = *(const float4*)(out + (size_t)t * HID + c4);
#pragma unroll
  for (int k = 0; k < TOPK; k++) {
    const int v = tIdx[t * TOPK + k];
    const int row = sb[v >> 10] + (v & 1023);
    const uint2 rv = *(const uint2*)(Rout + (size_t)row * HID + c4);
    o.x += bfu2f(rv.x & 0xffffu); o.y += bfu2f(rv.x >> 16);
    o.z += bfu2f(rv.y & 0xffffu); o.w += bfu2f(rv.y >> 16);
  }
  *(float4*)(out + (size_t)t * HID + c4) = o;
}

// ---------------------------------------------------------------------------
extern "C" void kernel_launch(void* const* d_in, const int* in_sizes, int n_in,
                              void* d_out, int out_size, void* d_ws, size_t ws_size,
                              hipStream_t stream) {
  const float* x      = (const float*)d_in[0];
  const float* rw     = (const float*)d_in[1];
  const float* w_gate = (const float*)d_in[2];
  const float* w_up   = (const float*)d_in[3];
  const float* w_down = (const float*)d_in[4];
  const float* ws_gu  = (const float*)d_in[5];
  const float* ws_dn  = (const float*)d_in[6];
  float* out = (float*)d_out;
  char* ws = (char*)d_ws;

  int*   counts = (int*)  (ws + OFF_COUNTS);
  int*   list   = (int*)  (ws + OFF_LIST);
  float* wtbuf  = (float*)(ws + OFF_WT);
  int*   tIdx   = (int*)  (ws + OFF_TIDX);
  unsigned short* Xb    = (unsigned short*)(ws + OFF_XB);
  unsigned short* Hr    = (unsigned short*)(ws + OFF_HR);
  unsigned short* Hs    = (unsigned short*)(ws + OFF_HS);
  unsigned short* WGUp  = (unsigned short*)(ws + OFF_WGU);
  unsigned short* WDp   = (unsigned short*)(ws + OFF_WD);
  unsigned short* WSGUp = (unsigned short*)(ws + OFF_WSGU);
  unsigned short* WSDp  = (unsigned short*)(ws + OFF_WSD);
  unsigned short* Rout  = (unsigned short*)(ws + OFF_ROUT);

  init_kernel<<<1, 64, 0, stream>>>(counts);
  router_kernel<<<T_TOK, 64, 0, stream>>>(x, rw, counts, list, wtbuf, tIdx, Xb);
  pack_all_kernel<<<6912, 256, 0, stream>>>(
      w_gate, w_up, w_down, ws_gu, ws_dn, WGUp, WDp, WSGUp, WSDp);
  phase1_kernel<<<dim3(16, 8, 17), 256, 0, stream>>>(
      Xb, WGUp, WSGUp, counts, list, wtbuf, Hr, Hs);
  phase2_kernel<<<dim3(8, 8, 17), 256, 0, stream>>>(
      Hr, Hs, WDp, WSDp, counts, Rout, out);
  combine_kernel<<<T_TOK, 256, 0, stream>>>(Rout, counts, tIdx, out);
  (void)in_sizes; (void)n_in; (void)out_size; (void)ws_size;
}